// Round 1
// baseline (166.551 us; speedup 1.0000x reference)
//
#include <hip/hip_runtime.h>

// Problem constants
#define HWC (512 * 512)          // H*W = 2^18
#define BATCH 4
#define NPIX (BATCH * HWC)       // total pixels = 1,048,576

// -------------------------------------------------------------------------
// Kernel 1: per-pixel math.
//   Inputs per pixel: x[3], m[6], R[6x6], D[6x6]
//   D_1 = inv(D); S1 = R D_1 R^T; need S1[:, :3] only.
//   X = D^{-1} * W where W[:,c] = row c of R (c=0..2)  -> LU solve, 3 RHS
//   S1c = R * X (6x3); Sxx = S1c[0:3], Syx = S1c[3:6]
//   Q = Syx * inv(Sxx)           (3x3 adjugate inverse)
//   dx = x - mx; z = [dx, Q dx]
//   z1 = R z; z1[0:3] *= -1; z2 = R^T z1 + m
//   out: x_ = z2[0:3], y_ = z2[3:6], m passthrough
// -------------------------------------------------------------------------
__global__ __launch_bounds__(256) void gpenc_math(
    const float* __restrict__ x,   // (B,3,HW)
    const float* __restrict__ m,   // (B,6,HW)
    const float* __restrict__ R,   // (B,HW,36)
    const float* __restrict__ Dm,  // (B,HW,36)
    float* __restrict__ xout,      // (B,3,HW)
    float* __restrict__ yout,      // (B,3,HW)
    float* __restrict__ mout)      // (B,6,HW)
{
    const int g = blockIdx.x * 256 + threadIdx.x;   // pixel id in [0, NPIX)
    const int b = g >> 18;                          // / HWC
    const int p = g & (HWC - 1);                    // % HWC

    // ---- load D, R (36 floats each, 144B contiguous, float4-aligned) ----
    float d[36], r[36];
    {
        const float4* D4 = reinterpret_cast<const float4*>(Dm + (size_t)g * 36);
        const float4* R4 = reinterpret_cast<const float4*>(R  + (size_t)g * 36);
#pragma unroll
        for (int i = 0; i < 9; ++i) {
            float4 v = D4[i];
            d[4*i+0] = v.x; d[4*i+1] = v.y; d[4*i+2] = v.z; d[4*i+3] = v.w;
            float4 w = R4[i];
            r[4*i+0] = w.x; r[4*i+1] = w.y; r[4*i+2] = w.z; r[4*i+3] = w.w;
        }
    }

    // ---- load x, m (plane-strided, coalesced across lanes) ----
    const size_t xb = (size_t)b * 3 * HWC + p;
    const size_t mb = (size_t)b * 6 * HWC + p;
    float xv[3], mv[6];
#pragma unroll
    for (int c = 0; c < 3; ++c) xv[c] = x[xb + (size_t)c * HWC];
#pragma unroll
    for (int c = 0; c < 6; ++c) mv[c] = m[mb + (size_t)c * HWC];

    // ---- LU factorization of D in place (no pivot; D ~ 2I, diag dominant) ----
    float rdiag[6];
#pragma unroll
    for (int k = 0; k < 6; ++k) {
        rdiag[k] = 1.0f / d[k*6 + k];
#pragma unroll
        for (int i = k + 1; i < 6; ++i) {
            float l = d[i*6 + k] * rdiag[k];
            d[i*6 + k] = l;
#pragma unroll
            for (int j = k + 1; j < 6; ++j) d[i*6 + j] -= l * d[k*6 + j];
        }
    }

    // ---- Solve D X = W, W[:,c] = R[c,:]^T (c = 0..2) -> X (6x3) ----
    float X[18];
#pragma unroll
    for (int c = 0; c < 3; ++c) {
        float t[6];
        // forward substitution (unit lower L)
#pragma unroll
        for (int i = 0; i < 6; ++i) {
            float s = r[c*6 + i];
#pragma unroll
            for (int j = 0; j < i; ++j) s -= d[i*6 + j] * t[j];
            t[i] = s;
        }
        // back substitution (U)
#pragma unroll
        for (int i = 5; i >= 0; --i) {
            float s = t[i];
#pragma unroll
            for (int j = i + 1; j < 6; ++j) s -= d[i*6 + j] * t[j];
            t[i] = s * rdiag[i];
        }
#pragma unroll
        for (int i = 0; i < 6; ++i) X[i*3 + c] = t[i];
    }

    // ---- S1c = R * X  (6x3) ----
    float s1[18];
#pragma unroll
    for (int i = 0; i < 6; ++i) {
#pragma unroll
        for (int c = 0; c < 3; ++c) {
            float s = 0.0f;
#pragma unroll
            for (int j = 0; j < 6; ++j) s += r[i*6 + j] * X[j*3 + c];
            s1[i*3 + c] = s;
        }
    }
    // Sxx = s1[0..2][*], Syx = s1[3..5][*]

    // ---- inv(Sxx) via adjugate ----
    const float a00 = s1[0], a01 = s1[1], a02 = s1[2];
    const float a10 = s1[3], a11 = s1[4], a12 = s1[5];
    const float a20 = s1[6], a21 = s1[7], a22 = s1[8];
    const float c00 =  (a11*a22 - a12*a21);
    const float c01 = -(a10*a22 - a12*a20);
    const float c02 =  (a10*a21 - a11*a20);
    const float det = a00*c00 + a01*c01 + a02*c02;
    const float rdet = 1.0f / det;
    float iS[9];
    iS[0] = c00 * rdet;
    iS[1] = -(a01*a22 - a02*a21) * rdet;
    iS[2] =  (a01*a12 - a02*a11) * rdet;
    iS[3] = c01 * rdet;
    iS[4] =  (a00*a22 - a02*a20) * rdet;
    iS[5] = -(a00*a12 - a02*a10) * rdet;
    iS[6] = c02 * rdet;
    iS[7] = -(a00*a21 - a01*a20) * rdet;
    iS[8] =  (a00*a11 - a01*a10) * rdet;

    // ---- Q = Syx * inv(Sxx)  (3x3) ----
    float Q[9];
#pragma unroll
    for (int mm = 0; mm < 3; ++mm) {
#pragma unroll
        for (int n = 0; n < 3; ++n) {
            float s = 0.0f;
#pragma unroll
            for (int k = 0; k < 3; ++k) s += s1[(3 + mm)*3 + k] * iS[k*3 + n];
            Q[mm*3 + n] = s;
        }
    }

    // ---- z = [dx, Q dx] ----
    float z[6];
#pragma unroll
    for (int n = 0; n < 3; ++n) z[n] = xv[n] - mv[n];
#pragma unroll
    for (int mm = 0; mm < 3; ++mm) {
        float s = 0.0f;
#pragma unroll
        for (int n = 0; n < 3; ++n) s += Q[mm*3 + n] * z[n];
        z[3 + mm] = s;
    }

    // ---- z1 = R z ; z1[0:3] *= -1 ; z2 = R^T z1 ; out = z2 + m ----
    float z1[6];
#pragma unroll
    for (int n = 0; n < 6; ++n) {
        float s = 0.0f;
#pragma unroll
        for (int mm = 0; mm < 6; ++mm) s += r[n*6 + mm] * z[mm];
        z1[n] = (n < 3) ? -s : s;
    }
    float z2[6];
#pragma unroll
    for (int n = 0; n < 6; ++n) {
        float s = 0.0f;
#pragma unroll
        for (int mm = 0; mm < 6; ++mm) s += z1[mm] * r[mm*6 + n];
        z2[n] = s + mv[n];
    }

    // ---- writes (coalesced plane-strided) ----
#pragma unroll
    for (int c = 0; c < 3; ++c) xout[xb + (size_t)c * HWC] = z2[c];
#pragma unroll
    for (int c = 0; c < 3; ++c) yout[xb + (size_t)c * HWC] = z2[3 + c];
#pragma unroll
    for (int c = 0; c < 6; ++c) mout[mb + (size_t)c * HWC] = mv[c];
}

// -------------------------------------------------------------------------
// Kernel 2: S_out = transpose(S, (0,3,4,1,2))
//   read 36 contiguous floats per pixel (float4 x9),
//   write 36 planes at stride HW (coalesced across lanes).
// -------------------------------------------------------------------------
__global__ __launch_bounds__(256) void gpenc_transpose(
    const float* __restrict__ S,   // (B,HW,36)
    float* __restrict__ Sout)      // (B,36,HW)
{
    const int g = blockIdx.x * 256 + threadIdx.x;
    const int b = g >> 18;
    const int p = g & (HWC - 1);
    const float4* S4 = reinterpret_cast<const float4*>(S + (size_t)g * 36);
    float* out = Sout + (size_t)b * 36 * HWC + p;
#pragma unroll
    for (int i = 0; i < 9; ++i) {
        float4 v = S4[i];
        out[(size_t)(4*i + 0) * HWC] = v.x;
        out[(size_t)(4*i + 1) * HWC] = v.y;
        out[(size_t)(4*i + 2) * HWC] = v.z;
        out[(size_t)(4*i + 3) * HWC] = v.w;
    }
}

extern "C" void kernel_launch(void* const* d_in, const int* in_sizes, int n_in,
                              void* d_out, int out_size, void* d_ws, size_t ws_size,
                              hipStream_t stream) {
    // setup_inputs order: x, y(unused), m, S, R, D
    const float* x  = (const float*)d_in[0];
    const float* m  = (const float*)d_in[2];
    const float* S  = (const float*)d_in[3];
    const float* R  = (const float*)d_in[4];
    const float* D  = (const float*)d_in[5];

    float* out = (float*)d_out;
    const size_t N3 = (size_t)BATCH * 3 * HWC;   // 3,145,728
    const size_t N6 = (size_t)BATCH * 6 * HWC;   // 6,291,456
    float* xout = out;
    float* yout = out + N3;
    float* mout = out + 2 * N3;
    float* Sout = out + 2 * N3 + N6;

    const int threads = 256;
    const int blocks = NPIX / threads;           // 4096

    gpenc_math<<<blocks, threads, 0, stream>>>(x, m, R, D, xout, yout, mout);
    gpenc_transpose<<<blocks, threads, 0, stream>>>(S, Sout);
}